// Round 2
// baseline (333.905 us; speedup 1.0000x reference)
//
#include <hip/hip_runtime.h>
#include <cstdint>
#include <cstddef>

#define N_NODES 50000
#define N_EDGES 800000
#define DIM_IN  128
#define DIM_OUT 64
#define SCAN_T  1024
#define CHUNK   ((N_NODES + SCAN_T - 1) / SCAN_T)   // 49

// ---------------------------------------------------------------------------
// Kernel 1: deg[n] = 0  (edge-only in-degree; self-loop added as +1 later)
// ---------------------------------------------------------------------------
__global__ __launch_bounds__(256) void k_zero(int* __restrict__ deg) {
    int i = blockIdx.x * 256 + threadIdx.x;
    if (i < N_NODES) deg[i] = 0;
}

// ---------------------------------------------------------------------------
// Kernel 2: in-degree histogram over dst (int atomics, L2-resident).
// ---------------------------------------------------------------------------
__global__ __launch_bounds__(256) void k_deg(const int* __restrict__ ei,
                                             int* __restrict__ deg) {
    int e = blockIdx.x * 256 + threadIdx.x;
    if (e < N_EDGES) atomicAdd(&deg[ei[N_EDGES + e]], 1);
}

// ---------------------------------------------------------------------------
// Kernel 3: single-block exclusive scan: offsets[n] = sum(deg[0..n)),
// fused dinv[n] = rsqrt(deg[n] + 1)  (+1 = self-loop).
// ---------------------------------------------------------------------------
__global__ __launch_bounds__(SCAN_T) void k_scan(const int* __restrict__ deg,
                                                 int* __restrict__ offsets,
                                                 float* __restrict__ dinv) {
    __shared__ int part[SCAN_T];
    const int t = threadIdx.x;
    const int begin = t * CHUNK;
    const int end = min(begin + CHUNK, N_NODES);

    int s = 0;
    for (int i = begin; i < end; ++i) s += deg[i];
    part[t] = s;
    __syncthreads();

    // Hillis-Steele inclusive scan over 1024 partials
    for (int off = 1; off < SCAN_T; off <<= 1) {
        int v = (t >= off) ? part[t - off] : 0;
        __syncthreads();
        if (t >= off) part[t] += v;
        __syncthreads();
    }

    int run = (t == 0) ? 0 : part[t - 1];
    for (int i = begin; i < end; ++i) {
        offsets[i] = run;            // exclusive start of bucket i
        int d = deg[i];
        run += d;
        dinv[i] = rsqrtf((float)(d + 1));
    }
}

// ---------------------------------------------------------------------------
// Kernel 4: h_scaled[n,:] = (x[n,:] @ W) * dinv[n]
// Block = 256 threads = 4 waves; 16 rows/block (4 rows/wave), lane = col.
// W (32 KB) + 16 x-rows (8 KB) in LDS. Xl reads are wave-uniform float4
// broadcasts (cheap); Wl reads are 64 consecutive floats (2 lanes/bank, free).
// 50000 / 16 = 3125 blocks exactly.
// ---------------------------------------------------------------------------
__global__ __launch_bounds__(256) void k_gemm(const float* __restrict__ x,
                                              const float* __restrict__ W,
                                              const float* __restrict__ dinv,
                                              float* __restrict__ h) {
    __shared__ float Wl[DIM_IN * DIM_OUT];   // [k][col], 32 KB
    __shared__ float Xl[16 * DIM_IN];        // [row][k], 8 KB

    const int t = threadIdx.x;
    const int rowBase = blockIdx.x * 16;

    for (int i = t; i < DIM_IN * DIM_OUT; i += 256) Wl[i] = W[i];
    const float* xg = x + (size_t)rowBase * DIM_IN;
    for (int i = t; i < 16 * DIM_IN; i += 256) Xl[i] = xg[i];
    __syncthreads();

    const int lane = t & 63;
    const int r0 = (t >> 6) * 4;

    float acc0 = 0.f, acc1 = 0.f, acc2 = 0.f, acc3 = 0.f;
#pragma unroll 4
    for (int k = 0; k < DIM_IN; k += 4) {
        const float w0 = Wl[(k + 0) * DIM_OUT + lane];
        const float w1 = Wl[(k + 1) * DIM_OUT + lane];
        const float w2 = Wl[(k + 2) * DIM_OUT + lane];
        const float w3 = Wl[(k + 3) * DIM_OUT + lane];
        const float4 a0 = *(const float4*)&Xl[(r0 + 0) * DIM_IN + k];
        const float4 a1 = *(const float4*)&Xl[(r0 + 1) * DIM_IN + k];
        const float4 a2 = *(const float4*)&Xl[(r0 + 2) * DIM_IN + k];
        const float4 a3 = *(const float4*)&Xl[(r0 + 3) * DIM_IN + k];
        acc0 = fmaf(a0.x, w0, acc0); acc0 = fmaf(a0.y, w1, acc0);
        acc0 = fmaf(a0.z, w2, acc0); acc0 = fmaf(a0.w, w3, acc0);
        acc1 = fmaf(a1.x, w0, acc1); acc1 = fmaf(a1.y, w1, acc1);
        acc1 = fmaf(a1.z, w2, acc1); acc1 = fmaf(a1.w, w3, acc1);
        acc2 = fmaf(a2.x, w0, acc2); acc2 = fmaf(a2.y, w1, acc2);
        acc2 = fmaf(a2.z, w2, acc2); acc2 = fmaf(a2.w, w3, acc2);
        acc3 = fmaf(a3.x, w0, acc3); acc3 = fmaf(a3.y, w1, acc3);
        acc3 = fmaf(a3.z, w2, acc3); acc3 = fmaf(a3.w, w3, acc3);
    }

    const int row = rowBase + r0;
    h[(size_t)(row + 0) * DIM_OUT + lane] = acc0 * dinv[row + 0];
    h[(size_t)(row + 1) * DIM_OUT + lane] = acc1 * dinv[row + 1];
    h[(size_t)(row + 2) * DIM_OUT + lane] = acc2 * dinv[row + 2];
    h[(size_t)(row + 3) * DIM_OUT + lane] = acc3 * dinv[row + 3];
}

// ---------------------------------------------------------------------------
// Kernel 5: CSR fill. pos = offsets[dst]++ (atomic); csr_src[pos] = src.
// After this kernel, offsets[n] == end(n) == start(n+1).
// ---------------------------------------------------------------------------
__global__ __launch_bounds__(256) void k_fill(const int* __restrict__ ei,
                                              int* __restrict__ offsets,
                                              int* __restrict__ csr_src) {
    int e = blockIdx.x * 256 + threadIdx.x;
    if (e < N_EDGES) {
        int src = ei[e];
        int dst = ei[N_EDGES + e];
        int pos = atomicAdd(&offsets[dst], 1);
        csr_src[pos] = src;
    }
}

// ---------------------------------------------------------------------------
// Kernel 6: gather-aggregate + bias + log_softmax, fused. One wave per node,
// lane = channel. out[n] = dinv[n]*(h[n] + sum_{e: dst=e} h[src_e]) + b,
// then log_softmax over 64 channels. No atomics; streaming writes.
// 50000 / 4 = 12500 blocks exactly.
// ---------------------------------------------------------------------------
__global__ __launch_bounds__(256) void k_agg(const int* __restrict__ offsets,
                                             const int* __restrict__ csr_src,
                                             const float* __restrict__ h,
                                             const float* __restrict__ dinv,
                                             const float* __restrict__ b,
                                             float* __restrict__ out) {
    const int n = blockIdx.x * 4 + (threadIdx.x >> 6);
    const int lane = threadIdx.x & 63;

    const int end   = offsets[n];                    // post-fill: end(n)
    const int start = (n == 0) ? 0 : offsets[n - 1]; // end(n-1) == start(n)

    float acc = h[(size_t)n * DIM_OUT + lane];       // self-loop term

    int i = start;
    for (; i + 4 <= end; i += 4) {
        const int s0 = csr_src[i + 0];
        const int s1 = csr_src[i + 1];
        const int s2 = csr_src[i + 2];
        const int s3 = csr_src[i + 3];
        const float v0 = h[(size_t)s0 * DIM_OUT + lane];
        const float v1 = h[(size_t)s1 * DIM_OUT + lane];
        const float v2 = h[(size_t)s2 * DIM_OUT + lane];
        const float v3 = h[(size_t)s3 * DIM_OUT + lane];
        acc += v0 + v1 + v2 + v3;
    }
    for (; i < end; ++i) acc += h[(size_t)csr_src[i] * DIM_OUT + lane];

    float v = acc * dinv[n] + b[lane];

    float m = v;
#pragma unroll
    for (int off = 32; off > 0; off >>= 1) m = fmaxf(m, __shfl_xor(m, off));
    float ex = __expf(v - m);
    float s = ex;
#pragma unroll
    for (int off = 32; off > 0; off >>= 1) s += __shfl_xor(s, off);

    out[(size_t)n * DIM_OUT + lane] = v - m - __logf(s);
}

// ---------------------------------------------------------------------------
extern "C" void kernel_launch(void* const* d_in, const int* in_sizes, int n_in,
                              void* d_out, int out_size, void* d_ws, size_t ws_size,
                              hipStream_t stream) {
    const float* x  = (const float*)d_in[0];
    const int*   ei = (const int*)d_in[1];   // [2, E]: row0 = src, row1 = dst
    const float* W  = (const float*)d_in[2];
    const float* b  = (const float*)d_in[3];
    float* out = (float*)d_out;

    // workspace: h (N*64 f32 = 12.8 MB) | dinv (N f32) | deg (N i32)
    //          | offsets (N i32) | csr_src (E i32 = 3.2 MB)
    char* ws = (char*)d_ws;
    float* h       = (float*)ws;                ws += (size_t)N_NODES * DIM_OUT * sizeof(float);
    float* dinv    = (float*)ws;                ws += (size_t)N_NODES * sizeof(float);
    int*   deg     = (int*)ws;                  ws += (size_t)N_NODES * sizeof(int);
    int*   offsets = (int*)ws;                  ws += (size_t)N_NODES * sizeof(int);
    int*   csr     = (int*)ws;

    k_zero<<<(N_NODES + 255) / 256, 256, 0, stream>>>(deg);
    k_deg <<<(N_EDGES + 255) / 256, 256, 0, stream>>>(ei, deg);
    k_scan<<<1, SCAN_T, 0, stream>>>(deg, offsets, dinv);
    k_gemm<<<N_NODES / 16, 256, 0, stream>>>(x, W, dinv, h);
    k_fill<<<(N_EDGES + 255) / 256, 256, 0, stream>>>(ei, offsets, csr);
    k_agg <<<N_NODES / 4, 256, 0, stream>>>(offsets, csr, h, dinv, b, out);
}

// Round 3
// 234.912 us; speedup vs baseline: 1.4214x; 1.4214x over previous
//
#include <hip/hip_runtime.h>
#include <cstdint>
#include <cstddef>

#define N_NODES 50000
#define N_EDGES 800000
#define DIM_IN  128
#define DIM_OUT 64
#define SB      ((N_NODES + 255) / 256)   // 196 scan blocks

// ---------------------------------------------------------------------------
// Kernel 1: deg[n] = 0
// ---------------------------------------------------------------------------
__global__ __launch_bounds__(256) void k_zero(int* __restrict__ deg) {
    int i = blockIdx.x * 256 + threadIdx.x;
    if (i < N_NODES) deg[i] = 0;
}

// ---------------------------------------------------------------------------
// Kernel 2: in-degree histogram over dst (int atomics, L2-resident).
// ---------------------------------------------------------------------------
__global__ __launch_bounds__(256) void k_deg(const int* __restrict__ ei,
                                             int* __restrict__ deg) {
    int e = blockIdx.x * 256 + threadIdx.x;
    if (e < N_EDGES) atomicAdd(&deg[ei[N_EDGES + e]], 1);
}

// ---------------------------------------------------------------------------
// Scan level 1: per-block (256-wide) reduction of deg → bsum[block].
// ---------------------------------------------------------------------------
__global__ __launch_bounds__(256) void k_part(const int* __restrict__ deg,
                                              int* __restrict__ bsum) {
    __shared__ int s[256];
    const int t = threadIdx.x;
    const int i = blockIdx.x * 256 + t;
    s[t] = (i < N_NODES) ? deg[i] : 0;
    __syncthreads();
#pragma unroll
    for (int off = 128; off > 0; off >>= 1) {
        if (t < off) s[t] += s[t + off];
        __syncthreads();
    }
    if (t == 0) bsum[blockIdx.x] = s[0];
}

// ---------------------------------------------------------------------------
// Scan level 2: one block scans SB (=196) block sums → exclusive bpre[].
// ---------------------------------------------------------------------------
__global__ __launch_bounds__(256) void k_mid(const int* __restrict__ bsum,
                                             int* __restrict__ bpre) {
    __shared__ int s[256];
    const int t = threadIdx.x;
    const int v = (t < SB) ? bsum[t] : 0;
    s[t] = v;
    __syncthreads();
#pragma unroll
    for (int off = 1; off < 256; off <<= 1) {
        int add = (t >= off) ? s[t - off] : 0;
        __syncthreads();
        s[t] += add;
        __syncthreads();
    }
    if (t < SB) bpre[t] = s[t] - v;   // exclusive prefix of block sums
}

// ---------------------------------------------------------------------------
// Scan level 3: in-block scan + block prefix → offsets; fused dinv.
// ---------------------------------------------------------------------------
__global__ __launch_bounds__(256) void k_emit(const int* __restrict__ deg,
                                              const int* __restrict__ bpre,
                                              int* __restrict__ offsets,
                                              float* __restrict__ dinv) {
    __shared__ int s[256];
    const int t = threadIdx.x;
    const int i = blockIdx.x * 256 + t;
    const int d = (i < N_NODES) ? deg[i] : 0;
    s[t] = d;
    __syncthreads();
#pragma unroll
    for (int off = 1; off < 256; off <<= 1) {
        int add = (t >= off) ? s[t - off] : 0;
        __syncthreads();
        s[t] += add;
        __syncthreads();
    }
    if (i < N_NODES) {
        offsets[i] = bpre[blockIdx.x] + s[t] - d;   // exclusive global prefix
        dinv[i] = rsqrtf((float)(d + 1));           // +1 = self-loop
    }
}

// ---------------------------------------------------------------------------
// GEMM: h_scaled[n,:] = (x[n,:] @ W) * dinv[n]. 16 rows/block, lane = col.
// ---------------------------------------------------------------------------
__global__ __launch_bounds__(256) void k_gemm(const float* __restrict__ x,
                                              const float* __restrict__ W,
                                              const float* __restrict__ dinv,
                                              float* __restrict__ h) {
    __shared__ float Wl[DIM_IN * DIM_OUT];   // [k][col], 32 KB
    __shared__ float Xl[16 * DIM_IN];        // [row][k], 8 KB

    const int t = threadIdx.x;
    const int rowBase = blockIdx.x * 16;

    for (int i = t; i < DIM_IN * DIM_OUT; i += 256) Wl[i] = W[i];
    const float* xg = x + (size_t)rowBase * DIM_IN;
    for (int i = t; i < 16 * DIM_IN; i += 256) Xl[i] = xg[i];
    __syncthreads();

    const int lane = t & 63;
    const int r0 = (t >> 6) * 4;

    float acc0 = 0.f, acc1 = 0.f, acc2 = 0.f, acc3 = 0.f;
#pragma unroll 4
    for (int k = 0; k < DIM_IN; k += 4) {
        const float w0 = Wl[(k + 0) * DIM_OUT + lane];
        const float w1 = Wl[(k + 1) * DIM_OUT + lane];
        const float w2 = Wl[(k + 2) * DIM_OUT + lane];
        const float w3 = Wl[(k + 3) * DIM_OUT + lane];
        const float4 a0 = *(const float4*)&Xl[(r0 + 0) * DIM_IN + k];
        const float4 a1 = *(const float4*)&Xl[(r0 + 1) * DIM_IN + k];
        const float4 a2 = *(const float4*)&Xl[(r0 + 2) * DIM_IN + k];
        const float4 a3 = *(const float4*)&Xl[(r0 + 3) * DIM_IN + k];
        acc0 = fmaf(a0.x, w0, acc0); acc0 = fmaf(a0.y, w1, acc0);
        acc0 = fmaf(a0.z, w2, acc0); acc0 = fmaf(a0.w, w3, acc0);
        acc1 = fmaf(a1.x, w0, acc1); acc1 = fmaf(a1.y, w1, acc1);
        acc1 = fmaf(a1.z, w2, acc1); acc1 = fmaf(a1.w, w3, acc1);
        acc2 = fmaf(a2.x, w0, acc2); acc2 = fmaf(a2.y, w1, acc2);
        acc2 = fmaf(a2.z, w2, acc2); acc2 = fmaf(a2.w, w3, acc2);
        acc3 = fmaf(a3.x, w0, acc3); acc3 = fmaf(a3.y, w1, acc3);
        acc3 = fmaf(a3.z, w2, acc3); acc3 = fmaf(a3.w, w3, acc3);
    }

    const int row = rowBase + r0;
    h[(size_t)(row + 0) * DIM_OUT + lane] = acc0 * dinv[row + 0];
    h[(size_t)(row + 1) * DIM_OUT + lane] = acc1 * dinv[row + 1];
    h[(size_t)(row + 2) * DIM_OUT + lane] = acc2 * dinv[row + 2];
    h[(size_t)(row + 3) * DIM_OUT + lane] = acc3 * dinv[row + 3];
}

// ---------------------------------------------------------------------------
// CSR fill. pos = offsets[dst]++ (atomic); csr_src[pos] = src.
// After this kernel, offsets[n] == end(n) == start(n+1).
// ---------------------------------------------------------------------------
__global__ __launch_bounds__(256) void k_fill(const int* __restrict__ ei,
                                              int* __restrict__ offsets,
                                              int* __restrict__ csr_src) {
    int e = blockIdx.x * 256 + threadIdx.x;
    if (e < N_EDGES) {
        int src = ei[e];
        int dst = ei[N_EDGES + e];
        int pos = atomicAdd(&offsets[dst], 1);
        csr_src[pos] = src;
    }
}

// ---------------------------------------------------------------------------
// Gather-aggregate + bias + log_softmax, fused. One wave per node, lane=chan.
// ---------------------------------------------------------------------------
__global__ __launch_bounds__(256) void k_agg(const int* __restrict__ offsets,
                                             const int* __restrict__ csr_src,
                                             const float* __restrict__ h,
                                             const float* __restrict__ dinv,
                                             const float* __restrict__ b,
                                             float* __restrict__ out) {
    const int n = blockIdx.x * 4 + (threadIdx.x >> 6);
    const int lane = threadIdx.x & 63;

    const int end   = offsets[n];                    // post-fill: end(n)
    const int start = (n == 0) ? 0 : offsets[n - 1]; // end(n-1) == start(n)

    float acc = h[(size_t)n * DIM_OUT + lane];       // self-loop term

    int i = start;
    for (; i + 4 <= end; i += 4) {
        const int s0 = csr_src[i + 0];
        const int s1 = csr_src[i + 1];
        const int s2 = csr_src[i + 2];
        const int s3 = csr_src[i + 3];
        const float v0 = h[(size_t)s0 * DIM_OUT + lane];
        const float v1 = h[(size_t)s1 * DIM_OUT + lane];
        const float v2 = h[(size_t)s2 * DIM_OUT + lane];
        const float v3 = h[(size_t)s3 * DIM_OUT + lane];
        acc += v0 + v1 + v2 + v3;
    }
    for (; i < end; ++i) acc += h[(size_t)csr_src[i] * DIM_OUT + lane];

    float v = acc * dinv[n] + b[lane];

    float m = v;
#pragma unroll
    for (int off = 32; off > 0; off >>= 1) m = fmaxf(m, __shfl_xor(m, off));
    float ex = __expf(v - m);
    float s = ex;
#pragma unroll
    for (int off = 32; off > 0; off >>= 1) s += __shfl_xor(s, off);

    out[(size_t)n * DIM_OUT + lane] = v - m - __logf(s);
}

// ---------------------------------------------------------------------------
extern "C" void kernel_launch(void* const* d_in, const int* in_sizes, int n_in,
                              void* d_out, int out_size, void* d_ws, size_t ws_size,
                              hipStream_t stream) {
    const float* x  = (const float*)d_in[0];
    const int*   ei = (const int*)d_in[1];   // [2, E]: row0 = src, row1 = dst
    const float* W  = (const float*)d_in[2];
    const float* b  = (const float*)d_in[3];
    float* out = (float*)d_out;

    // workspace: h (12.8 MB) | dinv | deg | offsets | bsum | bpre | csr_src
    char* ws = (char*)d_ws;
    float* h       = (float*)ws;  ws += (size_t)N_NODES * DIM_OUT * sizeof(float);
    float* dinv    = (float*)ws;  ws += (size_t)N_NODES * sizeof(float);
    int*   deg     = (int*)ws;    ws += (size_t)N_NODES * sizeof(int);
    int*   offsets = (int*)ws;    ws += (size_t)N_NODES * sizeof(int);
    int*   bsum    = (int*)ws;    ws += (size_t)SB * sizeof(int);
    int*   bpre    = (int*)ws;    ws += (size_t)SB * sizeof(int);
    int*   csr     = (int*)ws;

    k_zero<<<(N_NODES + 255) / 256, 256, 0, stream>>>(deg);
    k_deg <<<(N_EDGES + 255) / 256, 256, 0, stream>>>(ei, deg);
    k_part<<<SB, 256, 0, stream>>>(deg, bsum);
    k_mid <<<1, 256, 0, stream>>>(bsum, bpre);
    k_emit<<<SB, 256, 0, stream>>>(deg, bpre, offsets, dinv);
    k_gemm<<<N_NODES / 16, 256, 0, stream>>>(x, W, dinv, h);
    k_fill<<<(N_EDGES + 255) / 256, 256, 0, stream>>>(ei, offsets, csr);
    k_agg <<<N_NODES / 4, 256, 0, stream>>>(offsets, csr, h, dinv, b, out);
}